// Round 1
// baseline (1294.032 us; speedup 1.0000x reference)
//
#include <hip/hip_runtime.h>
#include <cstddef>
#include <cmath>

// Problem constants
#define B_    64
#define L_    128
#define V_    20000
#define D_    300
#define H_    256
#define NE_   34
#define NA_   36
#define M_    8192      // L_*B_
#define KP_   304       // D_ padded to multiple of 16
#define NPROJ_ 2048     // 2 dirs * 4H
#define K2_   512       // 2H
#define NCAT_ 128       // 36 (part_j) + 36 (part_i) + 34 (logit_h) padded to 128

__device__ __forceinline__ float sigmoidf_(float x) { return 1.0f / (1.0f + expf(-x)); }

typedef __attribute__((ext_vector_type(2))) _Float16 half2_;

__device__ __forceinline__ half2_ u2h(unsigned u) {
    union { unsigned u; half2_ h; } c; c.u = u; return c.h;
}
__device__ __forceinline__ unsigned packh2(float a, float b) {
    union { half2_ h; unsigned u; } c;
    c.h = half2_{(_Float16)a, (_Float16)b};
    return c.u;
}

#if __has_builtin(__builtin_amdgcn_fdot2)
__device__ __forceinline__ float fdot2_(half2_ a, half2_ b, float c) {
    return __builtin_amdgcn_fdot2(a, b, c, false);
}
#else
__device__ __forceinline__ float fdot2_(half2_ a, half2_ b, float c) {
    return c + (float)a.x * (float)b.x + (float)a.y * (float)b.y;
}
#endif

// ---------------------------------------------------------------------------
// K1: gather embeddings into X (M_ x KP_), zero-padded K tail. X[m][k], m = l*B_+b
__global__ __launch_bounds__(256) void k_gather(const float* __restrict__ emb,
                                                const int* __restrict__ ids,
                                                float* __restrict__ X) {
    int idx = blockIdx.x * 256 + threadIdx.x;
    if (idx >= M_ * KP_) return;
    int m = idx / KP_, k = idx - m * KP_;
    int l = m >> 6, b = m & 63;
    float v = 0.f;
    if (k < D_) {
        int tok = ids[b * L_ + l];
        v = emb[(size_t)tok * D_ + k];
    }
    X[idx] = v;
}

// K2: transposed input-proj weights Wt_ih (KP_ x NPROJ_) + combined bias
__global__ __launch_bounds__(256) void k_prep_wih(const float* __restrict__ Wf,
                                                  const float* __restrict__ Wb,
                                                  const float* __restrict__ bihf,
                                                  const float* __restrict__ bhhf,
                                                  const float* __restrict__ bihb,
                                                  const float* __restrict__ bhhb,
                                                  float* __restrict__ Wt,
                                                  float* __restrict__ bias) {
    int idx = blockIdx.x * 256 + threadIdx.x;
    if (idx >= KP_ * NPROJ_) return;
    int k = idx / NPROJ_, n = idx - k * NPROJ_;
    int dir = n >> 10, g = n & 1023;
    float v = 0.f;
    if (k < D_) v = dir ? Wb[g * D_ + k] : Wf[g * D_ + k];
    Wt[idx] = v;
    if (k == 0) bias[n] = dir ? (bihb[g] + bhhb[g]) : (bihf[g] + bhhf[g]);
}

// K3: pack W_hh to fp16 half2, k-major: Wp[dir][kp][g] = (W[g][2kp], W[g][2kp+1])
__global__ __launch_bounds__(256) void k_prep_whh16(const float* __restrict__ Wf,
                                                    const float* __restrict__ Wb,
                                                    unsigned* __restrict__ Wp) {
    int idx = blockIdx.x * 256 + threadIdx.x;       // 2*128*1024
    if (idx >= 2 * 128 * 1024) return;
    int dir = idx >> 17, r = idx & 131071;
    int kp = r >> 10, g = r & 1023;
    const float* W = dir ? Wb : Wf;
    Wp[idx] = packh2(W[g * H_ + 2 * kp], W[g * H_ + 2 * kp + 1]);
}

// K4: combined head weights Wcat (K2_ x NCAT_)
__global__ __launch_bounds__(256) void k_prep_wcat(const float* __restrict__ Warg,
                                                   const float* __restrict__ Wev,
                                                   const float* __restrict__ barg,
                                                   const float* __restrict__ bev,
                                                   float* __restrict__ Wcat,
                                                   float* __restrict__ bias) {
    int idx = blockIdx.x * 256 + threadIdx.x;
    if (idx >= K2_ * NCAT_) return;
    int k = idx >> 7, n = idx & 127;
    float v = 0.f;
    if (n < 36)       v = Warg[n * 1024 + k];
    else if (n < 72)  v = Warg[(n - 36) * 1024 + 512 + k];
    else if (n < 106) v = Wev[(n - 72) * 545 + k];
    Wcat[idx] = v;
    if (k == 0) {
        float bv = 0.f;
        if (n >= 36 && n < 72)       bv = barg[n - 36];
        else if (n >= 72 && n < 106) bv = bev[n - 72];
        bias[n] = bv;
    }
}

// ---------------------------------------------------------------------------
// Generic fp32 tiled GEMM: C (MxN) = A (MxK) * Bm (KxN) + bias[n]
template <int K>
__global__ __launch_bounds__(256) void k_gemm(const float* __restrict__ A,
                                              const float* __restrict__ Bm,
                                              const float* __restrict__ bias,
                                              float* __restrict__ C, int N) {
    __shared__ float As[16][64];
    __shared__ float Bs[16][64];
    const int tid = threadIdx.x;
    const int m0 = blockIdx.x * 64, n0 = blockIdx.y * 64;
    const int tx = tid & 15, ty = tid >> 4;
    const int a_m = tid >> 2;
    const int a_k = (tid & 3) << 2;
    const int b_k = tid >> 4;
    const int b_n = (tid & 15) << 2;

    float acc[4][4] = {};
    for (int k0 = 0; k0 < K; k0 += 16) {
        float4 av = *(const float4*)&A[(size_t)(m0 + a_m) * K + k0 + a_k];
        float4 bv = *(const float4*)&Bm[(size_t)(k0 + b_k) * N + n0 + b_n];
        __syncthreads();
        As[a_k][a_m] = av.x; As[a_k + 1][a_m] = av.y;
        As[a_k + 2][a_m] = av.z; As[a_k + 3][a_m] = av.w;
        *(float4*)&Bs[b_k][b_n] = bv;
        __syncthreads();
#pragma unroll
        for (int kk = 0; kk < 16; kk++) {
            float4 a4 = *(const float4*)&As[kk][ty << 2];
            float4 b4 = *(const float4*)&Bs[kk][tx << 2];
            float ar[4] = {a4.x, a4.y, a4.z, a4.w};
            float br[4] = {b4.x, b4.y, b4.z, b4.w};
#pragma unroll
            for (int i = 0; i < 4; i++)
#pragma unroll
                for (int j = 0; j < 4; j++) acc[i][j] += ar[i] * br[j];
        }
    }
    float4 bb = *(const float4*)&bias[n0 + (tx << 2)];
#pragma unroll
    for (int i = 0; i < 4; i++) {
        int m = m0 + (ty << 2) + i;
        float4 o;
        o.x = acc[i][0] + bb.x; o.y = acc[i][1] + bb.y;
        o.z = acc[i][2] + bb.z; o.w = acc[i][3] + bb.w;
        *(float4*)&C[(size_t)m * N + n0 + (tx << 2)] = o;
    }
}

// ---------------------------------------------------------------------------
// BiLSTM v4: same math as v3 (fp16-packed W_hh streamed from L2, fp32
// accumulate via v_dot2_f32_f16), but 16 waves per block via a 4-way K-split
// to fix the 1-wave/SIMD latency exposure (Occupancy 3% -> ~12%).
//   block = (dir, 2 batch rows); tid = (ks<<8)|t
//   thread (ks,t): partial dot for gates 4t..4t+3 over kp in [32ks, 32ks+32)
//   h-state kept as raw fp16 ushort[2][256] in LDS: a 4B read IS the half2.
//   Cell update by 512 threads (one per row x unit). 2 barriers/step.
__global__ __launch_bounds__(1024, 4) void k_lstm4(const float* __restrict__ pre,
                                                   const unsigned* __restrict__ Wp,
                                                   float* __restrict__ hs) {
    const int blk = blockIdx.x;            // 64 blocks
    const int dir = blk >> 5;
    const int b0 = (blk & 31) << 1;
    const int tid = threadIdx.x;
    const int ks = tid >> 8;               // K-slice 0..3
    const int t  = tid & 255;              // gate quad owner
    const unsigned* Wd = Wp + (size_t)dir * (128 * 1024);

    __shared__ __align__(16) unsigned short h16[2][256];   // h as raw fp16
    __shared__ __align__(16) float pbuf[4][2][1024];       // partial gate sums

    float c_state = 0.f;                   // live for tid < 512 (r = tid>>8, u = tid&255)
    if (tid < 512) h16[tid >> 8][tid & 255] = 0;
    __syncthreads();

    const unsigned* wbase = Wd + (ks << 15) + (t << 2);    // kp0 = 32*ks

    for (int step = 0; step < L_; ++step) {
        const int l = dir ? (L_ - 1 - step) : step;

        // ---- phase A: partial dots (all 16 waves) ----
        float4 a0, a1;
        if (ks == 0) {
            const float* p0 = pre + (size_t)(l * B_ + b0) * NPROJ_ + dir * 1024 + (t << 2);
            a0 = *(const float4*)p0;
            a1 = *(const float4*)(p0 + NPROJ_);
        } else {
            a0 = make_float4(0.f, 0.f, 0.f, 0.f);
            a1 = make_float4(0.f, 0.f, 0.f, 0.f);
        }
#pragma unroll
        for (int c8 = 0; c8 < 4; ++c8) {
            const int kp0 = (ks << 5) + (c8 << 3);         // base kp of this 8-chunk
            // 8 packed-half2 h values per row via two b128 broadcast reads
            uint4 hA0 = *(const uint4*)&h16[0][kp0 << 1];
            uint4 hB0 = *(const uint4*)&h16[0][(kp0 << 1) + 8];
            uint4 hA1 = *(const uint4*)&h16[1][kp0 << 1];
            uint4 hB1 = *(const uint4*)&h16[1][(kp0 << 1) + 8];
            unsigned hu0[8] = {hA0.x, hA0.y, hA0.z, hA0.w, hB0.x, hB0.y, hB0.z, hB0.w};
            unsigned hu1[8] = {hA1.x, hA1.y, hA1.z, hA1.w, hB1.x, hB1.y, hB1.z, hB1.w};
#pragma unroll
            for (int j = 0; j < 8; ++j) {
                uint4 w = *(const uint4*)(wbase + ((size_t)(c8 * 8 + j) << 10));
                half2_ h0 = u2h(hu0[j]);
                half2_ h1 = u2h(hu1[j]);
                a0.x = fdot2_(u2h(w.x), h0, a0.x);
                a0.y = fdot2_(u2h(w.y), h0, a0.y);
                a0.z = fdot2_(u2h(w.z), h0, a0.z);
                a0.w = fdot2_(u2h(w.w), h0, a0.w);
                a1.x = fdot2_(u2h(w.x), h1, a1.x);
                a1.y = fdot2_(u2h(w.y), h1, a1.y);
                a1.z = fdot2_(u2h(w.z), h1, a1.z);
                a1.w = fdot2_(u2h(w.w), h1, a1.w);
            }
        }
        *(float4*)&pbuf[ks][0][t << 2] = a0;
        *(float4*)&pbuf[ks][1][t << 2] = a1;
        __syncthreads();

        // ---- phase B: reduce + cell update (waves 0-7) ----
        if (tid < 512) {
            const int r = tid >> 8, u = tid & 255;
            float ig = (pbuf[0][r][u]          + pbuf[1][r][u])          + (pbuf[2][r][u]          + pbuf[3][r][u]);
            float fg = (pbuf[0][r][H_ + u]     + pbuf[1][r][H_ + u])     + (pbuf[2][r][H_ + u]     + pbuf[3][r][H_ + u]);
            float gg = (pbuf[0][r][2*H_ + u]   + pbuf[1][r][2*H_ + u])   + (pbuf[2][r][2*H_ + u]   + pbuf[3][r][2*H_ + u]);
            float og = (pbuf[0][r][3*H_ + u]   + pbuf[1][r][3*H_ + u])   + (pbuf[2][r][3*H_ + u]   + pbuf[3][r][3*H_ + u]);
            ig = sigmoidf_(ig);
            fg = sigmoidf_(fg);
            gg = tanhf(gg);
            og = sigmoidf_(og);
            float c = fg * c_state + ig * gg;
            c_state = c;
            float h = og * tanhf(c);
            hs[(size_t)(l * B_ + b0 + r) * 512 + dir * H_ + u] = h;
            union { _Float16 f; unsigned short us; } cv;
            cv.f = (_Float16)h;
            h16[r][u] = cv.us;
        }
        __syncthreads();
    }
}

// ---------------------------------------------------------------------------
// Event head sequential scan. One block (1 wave) per batch row.
__global__ __launch_bounds__(64) void k_event(const float* __restrict__ part,
                                              const float* __restrict__ Wev,
                                              float* __restrict__ out_ev) {
    const int b = blockIdx.x;
    const int e = threadIdx.x;
    __shared__ float sg[33];
    if (e < 33) sg[e] = 0.f;
    float wreg[33];
    if (e < NE_) {
#pragma unroll
        for (int j = 0; j < 33; j++) wreg[j] = Wev[e * 545 + 512 + j];
    }
    __syncthreads();
    for (int l = 0; l < L_; l++) {
        const int m = l * B_ + b;
        float v = -3.0e38f;
        if (e < NE_) {
            v = part[(size_t)m * NCAT_ + 72 + e];
#pragma unroll
            for (int j = 0; j < 33; j++) v += wreg[j] * sg[j];
            out_ev[((size_t)b * L_ + l) * NE_ + e] = v;
        }
        float bv = v;
        int bi = e;
#pragma unroll
        for (int off = 32; off > 0; off >>= 1) {
            float ov = __shfl_xor(bv, off, 64);
            int oi = __shfl_xor(bi, off, 64);
            if (ov > bv || (ov == bv && oi < bi)) { bv = ov; bi = oi; }
        }
        __syncthreads();
        if (bi > 0 && e == bi - 1) sg[e] = 1.f;
        __syncthreads();
    }
}

// ---------------------------------------------------------------------------
// Argument logits broadcast: out[b][i][j][a] = part_i[b][i][a] + part_j[b][j][a]
__global__ __launch_bounds__(256) void k_arg(const float* __restrict__ part,
                                             float* __restrict__ out) {
    const int blk = blockIdx.x;            // b*L_ + i
    const int b = blk >> 7, i = blk & 127;
    __shared__ float pj[L_ * NA_];
    __shared__ float pi_s[NA_];
    const int tid = threadIdx.x;
    if (tid < NA_) pi_s[tid] = part[(size_t)(i * B_ + b) * NCAT_ + 36 + tid];
    for (int idx = tid; idx < L_ * NA_; idx += 256) {
        int j = idx / NA_, a = idx - j * NA_;
        pj[idx] = part[(size_t)(j * B_ + b) * NCAT_ + a];
    }
    __syncthreads();
    float* o = out + (size_t)blk * (L_ * NA_);
    for (int idx = tid; idx < L_ * NA_; idx += 256) {
        int a = idx % NA_;
        o[idx] = pi_s[a] + pj[idx];
    }
}

// ---------------------------------------------------------------------------
extern "C" void kernel_launch(void* const* d_in, const int* in_sizes, int n_in,
                              void* d_out, int out_size, void* d_ws, size_t ws_size,
                              hipStream_t stream) {
    const float* emb  = (const float*)d_in[0];
    const float* Wihf = (const float*)d_in[1];
    const float* Whhf = (const float*)d_in[2];
    const float* bihf = (const float*)d_in[3];
    const float* bhhf = (const float*)d_in[4];
    const float* Wihb = (const float*)d_in[5];
    const float* Whhb = (const float*)d_in[6];
    const float* bihb = (const float*)d_in[7];
    const float* bhhb = (const float*)d_in[8];
    const float* Wev  = (const float*)d_in[9];
    const float* bev  = (const float*)d_in[10];
    const float* Warg = (const float*)d_in[11];
    const float* barg = (const float*)d_in[12];
    const int*   ids  = (const int*)d_in[13];
    float* out = (float*)d_out;
    float* ws  = (float*)d_ws;

    // Workspace layout (floats). X region reused for `part`.
    float*    X       = ws;                 // 8192*304
    float*    part    = ws;                 // 8192*128 (reuse)
    float*    Wt_ih   = ws + 2490368;       // 304*2048
    float*    bias_p  = ws + 3112960;       // 2048
    unsigned* Wp16    = (unsigned*)(ws + 3115008);  // 2*128*1024 uints (262144)
    float*    Wcat    = ws + 3639296;       // 512*128
    float*    bias_c  = ws + 3704832;       // 128
    float*    pre_all = ws + 3704960;       // 8192*2048
    float*    hsbuf   = ws + 20482176;      // 8192*512

    k_gather<<<(M_ * KP_) / 256, 256, 0, stream>>>(emb, ids, X);
    k_prep_wih<<<(KP_ * NPROJ_) / 256, 256, 0, stream>>>(Wihf, Wihb, bihf, bhhf, bihb, bhhb, Wt_ih, bias_p);
    k_prep_whh16<<<(2 * 128 * 1024) / 256, 256, 0, stream>>>(Whhf, Whhb, Wp16);
    k_prep_wcat<<<(K2_ * NCAT_) / 256, 256, 0, stream>>>(Warg, Wev, barg, bev, Wcat, bias_c);

    k_gemm<KP_><<<dim3(M_ / 64, NPROJ_ / 64), 256, 0, stream>>>(X, Wt_ih, bias_p, pre_all, NPROJ_);
    k_lstm4<<<64, 1024, 0, stream>>>(pre_all, Wp16, hsbuf);
    k_gemm<K2_><<<dim3(M_ / 64, NCAT_ / 64), 256, 0, stream>>>(hsbuf, Wcat, bias_c, part, NCAT_);
    k_event<<<B_, 64, 0, stream>>>(part, Wev, out);
    k_arg<<<B_ * L_, 256, 0, stream>>>(part, out + (size_t)B_ * L_ * NE_);
}